// Round 1
// baseline (652.410 us; speedup 1.0000x reference)
//
#include <hip/hip_runtime.h>

typedef __bf16 bf16x8 __attribute__((ext_vector_type(8)));
typedef float f32x4 __attribute__((ext_vector_type(4)));

__device__ __forceinline__ unsigned short f2bf(float f) {
  unsigned int u = __float_as_uint(f);
  u += 0x7fffu + ((u >> 16) & 1u);           // round-to-nearest-even
  return (unsigned short)(u >> 16);
}

// Convert the four 128x128 fp32 weight matrices to bf16 in workspace.
// Layout: Wq @ 0, Wk @ 16384, Wv @ 32768, Wo @ 49152 (elements).
__global__ __launch_bounds__(256) void wcvt(const float* __restrict__ Wq,
                                            const float* __restrict__ Wk,
                                            const float* __restrict__ Wv,
                                            const float* __restrict__ Wo,
                                            unsigned short* __restrict__ dst) {
  int i = blockIdx.x * 256 + threadIdx.x;    // 0..16383
  dst[i]          = f2bf(Wq[i]);
  dst[16384 + i]  = f2bf(Wk[i]);
  dst[32768 + i]  = f2bf(Wv[i]);
  dst[49152 + i]  = f2bf(Wo[i]);
}

// One block per node. 384 threads = 6 waves.
// Wave w owns m-tile-row w (rows 16w..16w+15 of the 96-row dimension).
__global__ __launch_bounds__(384, 2) void attn_kernel(
    const float* __restrict__ x, const float* __restrict__ bk,
    const float* __restrict__ bv, const float* __restrict__ bo,
    const unsigned short* __restrict__ Wbf, float* __restrict__ out) {
  // LDS: total 64512 bytes ( < 64 KiB -> 2 blocks/CU )
  __shared__ unsigned short Xs[96 * 136];   // x, bf16, stride 136 (pad for banks)
  __shared__ unsigned short Qs[96 * 32];    // Q_h (96 x 32); aliased as O_h in phases C/D
  __shared__ unsigned short Ks[96 * 32];    // K_h
  __shared__ unsigned short Vts[32 * 96];   // V_h transposed: Vt[d][t]
  __shared__ unsigned short Pas[96 * 104];  // P[q][k] bf16, stride 104

  const int tid  = threadIdx.x;
  const int wid  = tid >> 6;      // 0..5
  const int lane = tid & 63;
  const int quad = lane >> 4;     // 0..3
  const int l16  = lane & 15;
  const int node = blockIdx.x;

  // ---- stage x (fp32 global) -> bf16 LDS, coalesced float4 ----
  const float4* xb = (const float4*)(x + (size_t)node * (96 * 128));
  #pragma unroll
  for (int it = 0; it < 8; ++it) {
    int i4 = tid + it * 384;                 // 0..3071
    float4 v = xb[i4];
    int f = i4 << 2;
    int row = f >> 7, col = f & 127;
    ushort4 w;
    w.x = f2bf(v.x); w.y = f2bf(v.y); w.z = f2bf(v.z); w.w = f2bf(v.w);
    *(ushort4*)&Xs[row * 136 + col] = w;
  }

  f32x4 accO[8];
  #pragma unroll
  for (int i = 0; i < 8; ++i) accO[i] = (f32x4){0.f, 0.f, 0.f, 0.f};

  __syncthreads();

  // QKV phase ownership: waves (0,1)->Q, (2,3)->K, (4,5)->V; even wave: mt 0..2, odd: 3..5
  const int mat = wid >> 1;
  const int mt0 = (wid & 1) * 3;
  const unsigned short* Wmat  = Wbf + mat * 16384;
  const unsigned short* Wo_bf = Wbf + 3 * 16384;

  for (int h = 0; h < 4; ++h) {
    // ---- Phase A: {Q,K,V}_h = x @ W.T (+bias; bq cancels in softmax-over-q) ----
    bf16x8 bfr[2][4];
    #pragma unroll
    for (int nt = 0; nt < 2; ++nt)
      #pragma unroll
      for (int ks = 0; ks < 4; ++ks)
        bfr[nt][ks] = *(const bf16x8*)(Wmat + (size_t)(h * 32 + nt * 16 + l16) * 128 + ks * 32 + quad * 8);

    float bias0 = 0.f, bias1 = 0.f;
    if (mat == 1)      { bias0 = bk[h * 32 + l16]; bias1 = bk[h * 32 + 16 + l16]; }
    else if (mat == 2) { bias0 = bv[h * 32 + l16]; bias1 = bv[h * 32 + 16 + l16]; }

    #pragma unroll
    for (int m = 0; m < 3; ++m) {
      int mt = mt0 + m;
      f32x4 a0 = {0,0,0,0}, a1 = {0,0,0,0};
      #pragma unroll
      for (int ks = 0; ks < 4; ++ks) {
        bf16x8 afr = *(const bf16x8*)&Xs[(mt * 16 + l16) * 136 + ks * 32 + quad * 8];
        a0 = __builtin_amdgcn_mfma_f32_16x16x32_bf16(afr, bfr[0][ks], a0, 0, 0, 0);
        a1 = __builtin_amdgcn_mfma_f32_16x16x32_bf16(afr, bfr[1][ks], a1, 0, 0, 0);
      }
      if (mat == 0) {
        #pragma unroll
        for (int r = 0; r < 4; ++r) {
          Qs[(mt * 16 + quad * 4 + r) * 32 + l16]      = f2bf(a0[r]);
          Qs[(mt * 16 + quad * 4 + r) * 32 + 16 + l16] = f2bf(a1[r]);
        }
      } else if (mat == 1) {
        #pragma unroll
        for (int r = 0; r < 4; ++r) {
          Ks[(mt * 16 + quad * 4 + r) * 32 + l16]      = f2bf(a0[r] + bias0);
          Ks[(mt * 16 + quad * 4 + r) * 32 + 16 + l16] = f2bf(a1[r] + bias1);
        }
      } else {
        #pragma unroll
        for (int r = 0; r < 4; ++r) {
          Vts[l16 * 96        + mt * 16 + quad * 4 + r] = f2bf(a0[r] + bias0);
          Vts[(16 + l16) * 96 + mt * 16 + quad * 4 + r] = f2bf(a1[r] + bias1);
        }
      }
    }
    __syncthreads();

    // ---- Phase B: S' = K_h @ Q_h^T  (row = k, col = q); softmax over q = row-wise ----
    bf16x8 ak = *(const bf16x8*)&Ks[(wid * 16 + l16) * 32 + quad * 8];
    f32x4 s[6];
    #pragma unroll
    for (int qt = 0; qt < 6; ++qt) {
      bf16x8 bq8 = *(const bf16x8*)&Qs[(qt * 16 + l16) * 32 + quad * 8];
      f32x4 z = {0,0,0,0};
      s[qt] = __builtin_amdgcn_mfma_f32_16x16x32_bf16(ak, bq8, z, 0, 0, 0);
    }
    const float SC = 0.17677669529663687f * 1.4426950408889634f; // (1/sqrt(32))*log2(e)
    float rinv[4];
    #pragma unroll
    for (int r = 0; r < 4; ++r) {
      float mval = s[0][r];
      #pragma unroll
      for (int qt = 1; qt < 6; ++qt) mval = fmaxf(mval, s[qt][r]);
      #pragma unroll
      for (int d = 1; d < 16; d <<= 1) mval = fmaxf(mval, __shfl_xor(mval, d, 64));
      float sum = 0.f;
      #pragma unroll
      for (int qt = 0; qt < 6; ++qt) {
        float e = exp2f((s[qt][r] - mval) * SC);
        s[qt][r] = e;
        sum += e;
      }
      #pragma unroll
      for (int d = 1; d < 16; d <<= 1) sum += __shfl_xor(sum, d, 64);
      rinv[r] = 1.f / sum;
    }
    // write P[q][k] (A-layout for PV); wave w owns k-columns 16w..16w+15
    #pragma unroll
    for (int qt = 0; qt < 6; ++qt)
      #pragma unroll
      for (int r = 0; r < 4; ++r)
        Pas[(qt * 16 + l16) * 104 + wid * 16 + quad * 4 + r] = f2bf(s[qt][r] * rinv[r]);
    __syncthreads();

    // ---- Phase C: O_h = P @ V  (B-frags from Vt, contiguous in k) ----
    #pragma unroll
    for (int nt = 0; nt < 2; ++nt) {
      f32x4 acc = {0,0,0,0};
      #pragma unroll
      for (int ks = 0; ks < 3; ++ks) {
        bf16x8 ap  = *(const bf16x8*)&Pas[(wid * 16 + l16) * 104 + ks * 32 + quad * 8];
        bf16x8 bv8 = *(const bf16x8*)&Vts[(nt * 16 + l16) * 96 + ks * 32 + quad * 8];
        acc = __builtin_amdgcn_mfma_f32_16x16x32_bf16(ap, bv8, acc, 0, 0, 0);
      }
      #pragma unroll
      for (int r = 0; r < 4; ++r)   // O_h aliases Qs (Q_h dead after phase B)
        Qs[(wid * 16 + quad * 4 + r) * 32 + nt * 16 + l16] = f2bf(acc[r]);
    }
    // no barrier needed: phase D reads only this wave's own O_h rows

    // ---- Phase D: out += O_h @ Wo.T[h*32:(h+1)*32, :] ----
    bf16x8 ao = *(const bf16x8*)&Qs[(wid * 16 + l16) * 32 + quad * 8];
    #pragma unroll
    for (int nt = 0; nt < 8; ++nt) {
      bf16x8 bw = *(const bf16x8*)(Wo_bf + (size_t)(nt * 16 + l16) * 128 + h * 32 + quad * 8);
      accO[nt] = __builtin_amdgcn_mfma_f32_16x16x32_bf16(ao, bw, accO[nt], 0, 0, 0);
    }
    __syncthreads();   // protect Qs/Ks/Vts/Pas reuse by next head
  }

  // ---- epilogue: add bo, store fp32 ----
  float* ob = out + (size_t)node * (96 * 128);
  #pragma unroll
  for (int nt = 0; nt < 8; ++nt) {
    int col = nt * 16 + l16;
    float bias = bo[col];
    #pragma unroll
    for (int r = 0; r < 4; ++r) {
      int row = wid * 16 + quad * 4 + r;
      ob[row * 128 + col] = accO[nt][r] + bias;
    }
  }
}

extern "C" void kernel_launch(void* const* d_in, const int* in_sizes, int n_in,
                              void* d_out, int out_size, void* d_ws, size_t ws_size,
                              hipStream_t stream) {
  const float* x  = (const float*)d_in[0];
  const float* Wq = (const float*)d_in[1];
  // d_in[2] = bq: mathematically irrelevant (cancels in softmax over q)
  const float* Wk = (const float*)d_in[3];
  const float* bk = (const float*)d_in[4];
  const float* Wv = (const float*)d_in[5];
  const float* bv = (const float*)d_in[6];
  const float* Wo = (const float*)d_in[7];
  const float* bo = (const float*)d_in[8];
  int B_N = in_sizes[0] / (96 * 128);        // 4096

  unsigned short* Wbf = (unsigned short*)d_ws;  // 4 * 16384 bf16 = 128 KiB
  wcvt<<<64, 256, 0, stream>>>(Wq, Wk, Wv, Wo, Wbf);
  attn_kernel<<<B_N, 384, 0, stream>>>(x, bk, bv, bo, Wbf, (float*)d_out);
}